// Round 6
// baseline (15590.074 us; speedup 1.0000x reference)
//
#include <hip/hip_runtime.h>
#include <hip/hip_bf16.h>
#include <math.h>

#define BATCH 128
#define LEN   64000
#define FS    256
#define STEPS 200
#define NFILT 64
#define HID   512
#define HID2  512
#define NOUT  10
#define NF    320        // timesteps
#define G4    2048       // 4*HID2
#define KTOT  1024
#define KH    512        // K half per wave
#define NBLK  256        // persistent grid

typedef __bf16  bf16x8 __attribute__((ext_vector_type(8)));
typedef float   f32x4  __attribute__((ext_vector_type(4)));
typedef __hip_bfloat16 hbf;

// ---------------------------------------------------------------------------
// Fast transcendentals
// ---------------------------------------------------------------------------
__device__ __forceinline__ float fsig(float x) {
    return 1.f / (1.f + __expf(-x));
}
__device__ __forceinline__ float ftanh(float x) {
    return 1.f - 2.f / (__expf(2.f * x) + 1.f);
}
__device__ __forceinline__ void imulf_(float al, float au, float bl, float bu,
                                       float& lo, float& hi) {
    const float p1 = al * bl, p2 = al * bu, p3 = au * bl, p4 = au * bu;
    lo = fminf(fminf(p1, p2), fminf(p3, p4));
    hi = fmaxf(fmaxf(p1, p2), fmaxf(p3, p4));
}

// ---------------------------------------------------------------------------
// Device-coherent H access (sc-bit per-access coherence, no cache flushes).
// Weights/X stay plain-cached -> L2-resident.
// ---------------------------------------------------------------------------
__device__ __forceinline__ bf16x8 loadA16(const hbf* p, bool coh) {
    if (coh) {
        union { unsigned long long u[2]; bf16x8 v; } t;
        unsigned long long* q = (unsigned long long*)p;
        t.u[0] = __hip_atomic_load(q,     __ATOMIC_RELAXED, __HIP_MEMORY_SCOPE_AGENT);
        t.u[1] = __hip_atomic_load(q + 1, __ATOMIC_RELAXED, __HIP_MEMORY_SCOPE_AGENT);
        return t.v;
    }
    return *(const bf16x8*)p;
}
__device__ __forceinline__ void storeH(hbf* p, float v) {
    const __hip_bfloat16 h = __float2bfloat16(v);
    __hip_atomic_store((unsigned short*)p, *(const unsigned short*)&h,
                       __ATOMIC_RELAXED, __HIP_MEMORY_SCOPE_AGENT);
}

// ---------------------------------------------------------------------------
// Frontend: 8 (b,f)-rows per block, one wave per row. Writes bf16 c/r
// with layout [t][b][512].
// ---------------------------------------------------------------------------
__global__ __launch_bounds__(512) void frontend_kernel(
    const float* __restrict__ lb, const float* __restrict__ ub,
    const float* __restrict__ mtx1, const float* __restrict__ mtx2,
    const float* __restrict__ lin1_w, const float* __restrict__ lin1_b,
    hbf* __restrict__ Xc, hbf* __restrict__ Xr)
{
    const int tid  = threadIdx.x;
    const int r    = tid >> 6;
    const int lane = tid & 63;
    const int rowid = blockIdx.x * 8 + r;
    const int f = rowid % NF;
    const int b = rowid / NF;

    __shared__ float sc[8][FS], sr[8][FS];
    __shared__ float s2c[8][FS + 2], s2r[8][FS + 2];
    __shared__ float s3c[8][NFILT], s3r[8][NFILT];

    for (int i = lane; i < FS; i += 64) {
        const int pos = f * STEPS + i;
        float l = 0.f, u = 0.f;
        if (pos < LEN) {
            l = lb[(size_t)b * LEN + pos];
            u = ub[(size_t)b * LEN + pos];
        }
        sc[r][i] = 0.5f * (l + u);
        sr[r][i] = 0.5f * (u - l);
    }
    __syncthreads();

    for (int j = lane; j < FS + 2; j += 64) {
        float oc = 0.f, orr = 0.f;
#pragma unroll 4
        for (int i = 0; i < FS; ++i) {
            const float w = mtx1[i * (FS + 2) + j];
            oc  = fmaf(sc[r][i], w, oc);
            orr = fmaf(sr[r][i], fabsf(w), orr);
        }
        const float l1l = oc - orr, l1u = oc + orr;
        const float a = l1l * l1l, bb = l1u * l1u;
        const float squ = fmaxf(a, bb);
        const float sql = (l1l <= 0.f && l1u >= 0.f) ? 0.f : fminf(a, bb);
        s2c[r][j] = 0.5f * (sql + squ);
        s2r[r][j] = 0.5f * (squ - sql);
    }
    __syncthreads();

    {
        const int j = lane;
        float oc = 1e-10f, orr = 0.f;
#pragma unroll 4
        for (int i = 0; i < FS + 2; ++i) {
            const float w = mtx2[i * NFILT + j];
            oc  = fmaf(s2c[r][i], w, oc);
            orr = fmaf(s2r[r][i], fabsf(w), orr);
        }
        const float lgl = logf(oc - orr);
        const float lgu = logf(oc + orr);
        s3c[r][j] = 0.5f * (lgl + lgu);
        s3r[r][j] = 0.5f * (lgu - lgl);
    }
    __syncthreads();

    for (int j = lane; j < HID; j += 64) {
        float oc = lin1_b[j], orr = 0.f;
#pragma unroll 4
        for (int i = 0; i < NFILT; ++i) {
            const float w = lin1_w[i * HID + j];
            oc  = fmaf(s3c[r][i], w, oc);
            orr = fmaf(s3r[r][i], fabsf(w), orr);
        }
        const float n1l = oc - orr, n1u = oc + orr;
        const float rl = fmaxf(n1l, 0.f), ru = fmaxf(n1u, 0.f);
        const size_t o = ((size_t)f * BATCH + b) * HID + j;
        Xc[o] = __float2bfloat16(0.5f * (rl + ru));
        Xr[o] = __float2bfloat16(0.5f * (ru - rl));
    }
}

// ---------------------------------------------------------------------------
// Weight prep: Wt[n=2048][k=1024] bf16 and |Wt|; k<512 from w_ih, else w_hh.
// ---------------------------------------------------------------------------
__global__ __launch_bounds__(256) void prep_weights_kernel(
    const float* __restrict__ wih, const float* __restrict__ whh,
    hbf* __restrict__ Wt, hbf* __restrict__ Wta)
{
    __shared__ float tile[32][33];
    const int n0 = blockIdx.x * 32;
    const int k0 = blockIdx.y * 32;
    const int tx = threadIdx.x & 31;
    const int ty = threadIdx.x >> 5;

    for (int r = ty; r < 32; r += 8) {
        const int k = k0 + r;
        const float* src = (k < HID) ? (wih + (size_t)k * G4)
                                     : (whh + (size_t)(k - HID) * G4);
        tile[r][tx] = src[n0 + tx];
    }
    __syncthreads();
    for (int r = ty; r < 32; r += 8) {
        const int n = n0 + r;
        const float w = tile[tx][r];
        const size_t o = (size_t)n * KTOT + k0 + tx;
        Wt[o]  = __float2bfloat16(w);
        Wta[o] = __float2bfloat16(fabsf(w));
    }
}

// ---------------------------------------------------------------------------
// Grid-wide barrier, fence-free (relaxed agent atomics + s_waitcnt ordering).
// bar[0..7]=leaves (bid&7), bar[8]=root, bar[9]=generation, bar[16..23]=XCD
// registration tickets (written once at kernel start, reset by host memset).
// ---------------------------------------------------------------------------
__device__ __forceinline__ void grid_barrier(unsigned* bar, int bid, int tid) {
    __builtin_amdgcn_s_waitcnt(0);   // this wave's outstanding stores done
    __syncthreads();
    if (tid == 0) {
        const unsigned g = __hip_atomic_load(&bar[9], __ATOMIC_RELAXED,
                                             __HIP_MEMORY_SCOPE_AGENT);
        const unsigned a = __hip_atomic_fetch_add(&bar[bid & 7], 1u,
                                                  __ATOMIC_RELAXED,
                                                  __HIP_MEMORY_SCOPE_AGENT);
        bool released = false;
        if (a == 31u) {
            const unsigned r = __hip_atomic_fetch_add(&bar[8], 1u,
                                                      __ATOMIC_RELAXED,
                                                      __HIP_MEMORY_SCOPE_AGENT);
            if (r == 7u) {
                for (int i = 0; i < 9; ++i)
                    __hip_atomic_store(&bar[i], 0u, __ATOMIC_RELAXED,
                                       __HIP_MEMORY_SCOPE_AGENT);
                __builtin_amdgcn_s_waitcnt(0);
                __hip_atomic_fetch_add(&bar[9], 1u, __ATOMIC_RELAXED,
                                       __HIP_MEMORY_SCOPE_AGENT);
                released = true;
            }
        }
        if (!released) {
            while (__hip_atomic_load(&bar[9], __ATOMIC_RELAXED,
                                     __HIP_MEMORY_SCOPE_AGENT) == g)
                __builtin_amdgcn_s_sleep(1);
        }
        asm volatile("" ::: "memory");
    }
    __syncthreads();
}

// ---------------------------------------------------------------------------
// One GEMM phase for one wave: K-half dual-gate MFMA into red[w].
// ---------------------------------------------------------------------------
__device__ __forceinline__ void gemm_phase(
    const hbf* __restrict__ aptr, bool coh,
    const hbf* const wp[4], int lane, float red[4][64][4])
{
    f32x4 a0{0,0,0,0}, a1{0,0,0,0}, a2{0,0,0,0}, a3{0,0,0,0};
#pragma unroll 4
    for (int kk = 0; kk < KH; kk += 32) {
        const bf16x8 av = loadA16(aptr + kk, coh);
        a0 = __builtin_amdgcn_mfma_f32_16x16x32_bf16(av, *(const bf16x8*)(wp[0] + kk), a0, 0, 0, 0);
        a1 = __builtin_amdgcn_mfma_f32_16x16x32_bf16(av, *(const bf16x8*)(wp[1] + kk), a1, 0, 0, 0);
        a2 = __builtin_amdgcn_mfma_f32_16x16x32_bf16(av, *(const bf16x8*)(wp[2] + kk), a2, 0, 0, 0);
        a3 = __builtin_amdgcn_mfma_f32_16x16x32_bf16(av, *(const bf16x8*)(wp[3] + kk), a3, 0, 0, 0);
    }
    *((f32x4*)&red[0][lane][0]) = a0;
    *((f32x4*)&red[1][lane][0]) = a1;
    *((f32x4*)&red[2][lane][0]) = a2;
    *((f32x4*)&red[3][lane][0]) = a3;
}

// ---------------------------------------------------------------------------
// Cell phase: one thread per (m, j); c-state lives in registers.
// ---------------------------------------------------------------------------
__device__ __forceinline__ void cell_phase(
    float red[4][4][64][4], const float* __restrict__ bias,
    int j0, int m0, int tid,
    float& cl_r, float& cu_r,
    hbf* __restrict__ Hco, hbf* __restrict__ Hro,
    float* __restrict__ hl, float* __restrict__ hu, bool writeF)
{
    const int m  = tid >> 4;
    const int j  = tid & 15;
    const int ll = ((m >> 2) << 4) | j;
    const int rr = m & 3;

    float gl[4], gu[4];
#pragma unroll
    for (int g = 0; g < 4; ++g) {
        const float C = red[0][g][ll][rr] + red[2][g][ll][rr];
        const float R = red[1][g][ll][rr] + red[3][g][ll][rr];
        const float bs = bias[g * HID2 + j0 + j];
        gl[g] = C - R + bs;
        gu[g] = C + R + bs;
    }

    const float il = fsig(gl[0]), iu = fsig(gu[0]);
    const float fl = fsig(gl[1]), fu = fsig(gu[1]);
    const float ggl = ftanh(gl[2]), ggu = ftanh(gu[2]);
    const float ol = fsig(gl[3]), ou = fsig(gu[3]);

    float fcl, fcu, igl, igu;
    imulf_(fl, fu, cl_r, cu_r, fcl, fcu);
    imulf_(il, iu, ggl, ggu, igl, igu);
    const float ncl = fcl + igl, ncu = fcu + igu;
    cl_r = ncl; cu_r = ncu;

    float nhl, nhu;
    imulf_(ol, ou, ftanh(ncl), ftanh(ncu), nhl, nhu);
    const int idx = (m0 + m) * HID2 + j0 + j;
    storeH(&Hco[idx], 0.5f * (nhl + nhu));
    storeH(&Hro[idx], 0.5f * (nhu - nhl));
    if (writeF) {
        hl[idx] = nhl;
        hu[idx] = nhu;
    }
}

// ---------------------------------------------------------------------------
// Persistent LSTM. Tile assignment is PHYSICAL-XCD-aware: each block reads
// its XCC_ID from hardware, takes a per-XCD ticket, and after one barrier
// converts (prefix sum of counts + slot) into a unique tile id such that
// blocks on the same physical XCD own contiguous j-slices -> per-XCD weight
// working set ~2 MB stays L2-resident under ANY dispatch mapping.
// ---------------------------------------------------------------------------
__global__ __launch_bounds__(256) void lstm_persistent(
    const hbf* __restrict__ Xc, const hbf* __restrict__ Xr,
    const hbf* __restrict__ Wt0, const hbf* __restrict__ Wt0a,
    const hbf* __restrict__ Wt1, const hbf* __restrict__ Wt1a,
    const float* __restrict__ b0, const float* __restrict__ b1,
    hbf* __restrict__ H0c0, hbf* __restrict__ H0r0,
    hbf* __restrict__ H0c1, hbf* __restrict__ H0r1,
    hbf* __restrict__ H1c0, hbf* __restrict__ H1r0,
    hbf* __restrict__ H1c1, hbf* __restrict__ H1r1,
    float* __restrict__ h1l, float* __restrict__ h1u,
    unsigned* __restrict__ bar)
{
    const int tid  = threadIdx.x;
    const int bid  = blockIdx.x;

    __shared__ unsigned s_tile;
    __shared__ float red[4][4][64][4];    // 16 KB

    // ---- physical-XCD registration ----
    if (tid == 0) {
        unsigned xcc;
        asm volatile("s_getreg_b32 %0, hwreg(HW_REG_XCC_ID)" : "=s"(xcc));
        xcc &= 7u;
        const unsigned slot = __hip_atomic_fetch_add(
            &bar[16 + xcc], 1u, __ATOMIC_RELAXED, __HIP_MEMORY_SCOPE_AGENT);
        s_tile = (xcc << 16) | slot;
    }
    grid_barrier(bar, bid, tid);          // all registrations done
    if (tid == 0) {
        const unsigned xcc = s_tile >> 16, slot = s_tile & 0xffffu;
        unsigned base = 0;
        for (unsigned y = 0; y < xcc; ++y)
            base += __hip_atomic_load(&bar[16 + y], __ATOMIC_RELAXED,
                                      __HIP_MEMORY_SCOPE_AGENT);
        s_tile = base + slot;             // unique in [0, 256)
    }
    __syncthreads();

    const unsigned tile = s_tile;
    const int j0 = (int)(tile >> 3) * 16;     // same-XCD blocks share j-slices
    const int m0 = (int)(tile & 7) * 16;

    const int w    = tid >> 6;
    const int lane = tid & 63;
    const int op   = w & 1;               // 0 center, 1 radius
    const int ks   = w >> 1;              // K half
    const int rc   = lane & 15;
    const int gk   = lane >> 4;

    const hbf* WbL0 = op ? Wt0a : Wt0;
    const hbf* WbL1 = op ? Wt1a : Wt1;
    const hbf* wp0[4];
    const hbf* wp1[4];
#pragma unroll
    for (int g = 0; g < 4; ++g) {
        const size_t row = (size_t)(g * HID2 + j0 + rc) * KTOT + ks * KH + 8 * gk;
        wp0[g] = WbL0 + row;
        wp1[g] = WbL1 + row;
    }

    hbf* H0cb[2] = {H0c0, H0c1};
    hbf* H0rb[2] = {H0r0, H0r1};
    hbf* H1cb[2] = {H1c0, H1c1};
    hbf* H1rb[2] = {H1r0, H1r1};

    const int arow_off = (m0 + rc) * HID + 8 * gk;

    float c0l_r = 0.f, c0u_r = 0.f, c1l_r = 0.f, c1u_r = 0.f;

    for (int t = 0; t < NF; ++t) {
        const int rd = t & 1, wr2 = rd ^ 1;

        // ---- layer 0: x = X[t] (plain cached), h = H0[rd] (coherent) ----
        {
            const hbf* Ab;
            bool coh;
            if (ks == 0) {
                Ab = (op ? Xr : Xc) + (size_t)t * BATCH * HID;
                coh = false;
            } else {
                Ab = op ? H0rb[rd] : H0cb[rd];
                coh = true;
            }
            gemm_phase(Ab + arow_off, coh, wp0, lane, red[w]);
        }
        __syncthreads();
        cell_phase(red, b0, j0, m0, tid, c0l_r, c0u_r,
                   H0cb[wr2], H0rb[wr2], nullptr, nullptr, false);
        grid_barrier(bar, bid, tid);

        // ---- layer 1: x = H0[wr2], h = H1[rd] (both coherent) ----
        {
            const hbf* Ab;
            if (ks == 0)
                Ab = op ? H0rb[wr2] : H0cb[wr2];
            else
                Ab = op ? H1rb[rd] : H1cb[rd];
            gemm_phase(Ab + arow_off, true, wp1, lane, red[w]);
        }
        __syncthreads();
        cell_phase(red, b1, j0, m0, tid, c1l_r, c1u_r,
                   H1cb[wr2], H1rb[wr2], h1l, h1u, t == NF - 1);
        grid_barrier(bar, bid, tid);
    }
}

// ---------------------------------------------------------------------------
// Final 512 -> 10 interval linear
// ---------------------------------------------------------------------------
__global__ __launch_bounds__(64) void final_kernel(
    const float* __restrict__ h1l, const float* __restrict__ h1u,
    const float* __restrict__ w, const float* __restrict__ bias,
    float* __restrict__ out)
{
    const int b = blockIdx.x;
    const int j = threadIdx.x;
    if (j < NOUT) {
        float oc = bias[j], orr = 0.f;
        for (int i = 0; i < HID2; ++i) {
            const float lo = h1l[(size_t)b * HID2 + i];
            const float hi = h1u[(size_t)b * HID2 + i];
            const float wv = w[i * NOUT + j];
            oc  = fmaf(0.5f * (lo + hi), wv, oc);
            orr = fmaf(0.5f * (hi - lo), fabsf(wv), orr);
        }
        out[b * NOUT + j] = oc - orr;
        out[BATCH * NOUT + b * NOUT + j] = oc + orr;
    }
}

// ---------------------------------------------------------------------------
extern "C" void kernel_launch(void* const* d_in, const int* in_sizes, int n_in,
                              void* d_out, int out_size, void* d_ws, size_t ws_size,
                              hipStream_t stream)
{
    const float* input_lb = (const float*)d_in[0];
    const float* input_ub = (const float*)d_in[1];
    const float* mtx1     = (const float*)d_in[2];
    const float* mtx2     = (const float*)d_in[3];
    const float* lin1_w   = (const float*)d_in[4];
    const float* lin1_b   = (const float*)d_in[5];
    const float* w_ih0    = (const float*)d_in[6];
    const float* w_hh0    = (const float*)d_in[7];
    const float* b0       = (const float*)d_in[8];
    const float* w_ih1    = (const float*)d_in[9];
    const float* w_hh1    = (const float*)d_in[10];
    const float* b1       = (const float*)d_in[11];
    const float* lin2_w   = (const float*)d_in[12];
    const float* lin2_b   = (const float*)d_in[13];
    float* out = (float*)d_out;

    char* ws = (char*)d_ws;
    size_t off = 0;
    hbf* Xc = (hbf*)(ws + off); off += (size_t)NF * BATCH * HID * 2;
    hbf* Xr = (hbf*)(ws + off); off += (size_t)NF * BATCH * HID * 2;
    hbf* Wt0  = (hbf*)(ws + off); off += (size_t)G4 * KTOT * 2;
    hbf* Wt0a = (hbf*)(ws + off); off += (size_t)G4 * KTOT * 2;
    hbf* Wt1  = (hbf*)(ws + off); off += (size_t)G4 * KTOT * 2;
    hbf* Wt1a = (hbf*)(ws + off); off += (size_t)G4 * KTOT * 2;

    // zeroed region: H ping-pong (bf16) + barrier/ticket words
    char* zero_base = ws + off;
    const size_t HSZ = (size_t)BATCH * HID2;
    hbf* H0c[2]; hbf* H0r[2]; hbf* H1c[2]; hbf* H1r[2];
    for (int i = 0; i < 2; ++i) {
        H0c[i] = (hbf*)(ws + off); off += HSZ * 2;
        H0r[i] = (hbf*)(ws + off); off += HSZ * 2;
        H1c[i] = (hbf*)(ws + off); off += HSZ * 2;
        H1r[i] = (hbf*)(ws + off); off += HSZ * 2;
    }
    unsigned* bar = (unsigned*)(ws + off); off += 128;   // 32 words
    const size_t zero_bytes = (size_t)((ws + off) - zero_base);
    float* h1l = (float*)(ws + off); off += HSZ * 4;
    float* h1u = (float*)(ws + off); off += HSZ * 4;

    hipMemsetAsync(zero_base, 0, zero_bytes, stream);

    {
        const dim3 pgrid(G4 / 32, KTOT / 32);
        prep_weights_kernel<<<pgrid, 256, 0, stream>>>(w_ih0, w_hh0, Wt0, Wt0a);
        prep_weights_kernel<<<pgrid, 256, 0, stream>>>(w_ih1, w_hh1, Wt1, Wt1a);
    }

    frontend_kernel<<<(BATCH * NF) / 8, 512, 0, stream>>>(
        input_lb, input_ub, mtx1, mtx2, lin1_w, lin1_b, Xc, Xr);

    lstm_persistent<<<NBLK, 256, 0, stream>>>(
        Xc, Xr, Wt0, Wt0a, Wt1, Wt1a, b0, b1,
        H0c[0], H0r[0], H0c[1], H0r[1],
        H1c[0], H1r[0], H1c[1], H1r[1],
        h1l, h1u, bar);

    final_kernel<<<BATCH, 64, 0, stream>>>(h1l, h1u, lin2_w, lin2_b, out);
}

// Round 7
// 7231.297 us; speedup vs baseline: 2.1559x; 2.1559x over previous
//
#include <hip/hip_runtime.h>
#include <hip/hip_bf16.h>
#include <math.h>

#define BATCH 128
#define LEN   64000
#define FS    256
#define STEPS 200
#define NFILT 64
#define HID   512
#define HID2  512
#define NOUT  10
#define NF    320        // timesteps
#define G4    2048       // 4*HID2
#define KTOT  1024
#define KH    512        // K half per wave
#define NBLK  256        // persistent grid

typedef __bf16  bf16x8 __attribute__((ext_vector_type(8)));
typedef float   f32x4  __attribute__((ext_vector_type(4)));
typedef __hip_bfloat16 hbf;

// barrier-word layout (unsigned words, 64B-line stride 16)
#define TKT(i)  ((i) * 16)            // 8 XCD tickets
#define ARV(b)  (128 + (b) * 16)      // 256 arrive flags
#define REL(i)  (128 + 4096 + (i) * 16) // 8 release flags
#define BAR_WORDS (128 + 4096 + 128)

// ---------------------------------------------------------------------------
// Fast transcendentals
// ---------------------------------------------------------------------------
__device__ __forceinline__ float fsig(float x) {
    return 1.f / (1.f + __expf(-x));
}
__device__ __forceinline__ float ftanh(float x) {
    return 1.f - 2.f / (__expf(2.f * x) + 1.f);
}
__device__ __forceinline__ void imulf_(float al, float au, float bl, float bu,
                                       float& lo, float& hi) {
    const float p1 = al * bl, p2 = al * bu, p3 = au * bl, p4 = au * bu;
    lo = fminf(fminf(p1, p2), fminf(p3, p4));
    hi = fmaxf(fmaxf(p1, p2), fmaxf(p3, p4));
}

// ---------------------------------------------------------------------------
// Device-coherent H access (sc-bit per-access coherence, no cache flushes).
// ---------------------------------------------------------------------------
__device__ __forceinline__ bf16x8 loadA16(const hbf* p, bool coh) {
    if (coh) {
        union { unsigned long long u[2]; bf16x8 v; } t;
        unsigned long long* q = (unsigned long long*)p;
        t.u[0] = __hip_atomic_load(q,     __ATOMIC_RELAXED, __HIP_MEMORY_SCOPE_AGENT);
        t.u[1] = __hip_atomic_load(q + 1, __ATOMIC_RELAXED, __HIP_MEMORY_SCOPE_AGENT);
        return t.v;
    }
    return *(const bf16x8*)p;
}
__device__ __forceinline__ void storeH(hbf* p, float v) {
    const __hip_bfloat16 h = __float2bfloat16(v);
    __hip_atomic_store((unsigned short*)p, *(const unsigned short*)&h,
                       __ATOMIC_RELAXED, __HIP_MEMORY_SCOPE_AGENT);
}

// ---------------------------------------------------------------------------
// Frontend: 8 (b,f)-rows per block, one wave per row. Writes bf16 c/r
// with layout [t][b][512].
// ---------------------------------------------------------------------------
__global__ __launch_bounds__(512) void frontend_kernel(
    const float* __restrict__ lb, const float* __restrict__ ub,
    const float* __restrict__ mtx1, const float* __restrict__ mtx2,
    const float* __restrict__ lin1_w, const float* __restrict__ lin1_b,
    hbf* __restrict__ Xc, hbf* __restrict__ Xr)
{
    const int tid  = threadIdx.x;
    const int r    = tid >> 6;
    const int lane = tid & 63;
    const int rowid = blockIdx.x * 8 + r;
    const int f = rowid % NF;
    const int b = rowid / NF;

    __shared__ float sc[8][FS], sr[8][FS];
    __shared__ float s2c[8][FS + 2], s2r[8][FS + 2];
    __shared__ float s3c[8][NFILT], s3r[8][NFILT];

    for (int i = lane; i < FS; i += 64) {
        const int pos = f * STEPS + i;
        float l = 0.f, u = 0.f;
        if (pos < LEN) {
            l = lb[(size_t)b * LEN + pos];
            u = ub[(size_t)b * LEN + pos];
        }
        sc[r][i] = 0.5f * (l + u);
        sr[r][i] = 0.5f * (u - l);
    }
    __syncthreads();

    for (int j = lane; j < FS + 2; j += 64) {
        float oc = 0.f, orr = 0.f;
#pragma unroll 4
        for (int i = 0; i < FS; ++i) {
            const float w = mtx1[i * (FS + 2) + j];
            oc  = fmaf(sc[r][i], w, oc);
            orr = fmaf(sr[r][i], fabsf(w), orr);
        }
        const float l1l = oc - orr, l1u = oc + orr;
        const float a = l1l * l1l, bb = l1u * l1u;
        const float squ = fmaxf(a, bb);
        const float sql = (l1l <= 0.f && l1u >= 0.f) ? 0.f : fminf(a, bb);
        s2c[r][j] = 0.5f * (sql + squ);
        s2r[r][j] = 0.5f * (squ - sql);
    }
    __syncthreads();

    {
        const int j = lane;
        float oc = 1e-10f, orr = 0.f;
#pragma unroll 4
        for (int i = 0; i < FS + 2; ++i) {
            const float w = mtx2[i * NFILT + j];
            oc  = fmaf(s2c[r][i], w, oc);
            orr = fmaf(s2r[r][i], fabsf(w), orr);
        }
        const float lgl = logf(oc - orr);
        const float lgu = logf(oc + orr);
        s3c[r][j] = 0.5f * (lgl + lgu);
        s3r[r][j] = 0.5f * (lgu - lgl);
    }
    __syncthreads();

    for (int j = lane; j < HID; j += 64) {
        float oc = lin1_b[j], orr = 0.f;
#pragma unroll 4
        for (int i = 0; i < NFILT; ++i) {
            const float w = lin1_w[i * HID + j];
            oc  = fmaf(s3c[r][i], w, oc);
            orr = fmaf(s3r[r][i], fabsf(w), orr);
        }
        const float n1l = oc - orr, n1u = oc + orr;
        const float rl = fmaxf(n1l, 0.f), ru = fmaxf(n1u, 0.f);
        const size_t o = ((size_t)f * BATCH + b) * HID + j;
        Xc[o] = __float2bfloat16(0.5f * (rl + ru));
        Xr[o] = __float2bfloat16(0.5f * (ru - rl));
    }
}

// ---------------------------------------------------------------------------
// Weight prep: Wt[n=2048][k=1024] bf16 and |Wt|; k<512 from w_ih, else w_hh.
// ---------------------------------------------------------------------------
__global__ __launch_bounds__(256) void prep_weights_kernel(
    const float* __restrict__ wih, const float* __restrict__ whh,
    hbf* __restrict__ Wt, hbf* __restrict__ Wta)
{
    __shared__ float tile[32][33];
    const int n0 = blockIdx.x * 32;
    const int k0 = blockIdx.y * 32;
    const int tx = threadIdx.x & 31;
    const int ty = threadIdx.x >> 5;

    for (int r = ty; r < 32; r += 8) {
        const int k = k0 + r;
        const float* src = (k < HID) ? (wih + (size_t)k * G4)
                                     : (whh + (size_t)(k - HID) * G4);
        tile[r][tx] = src[n0 + tx];
    }
    __syncthreads();
    for (int r = ty; r < 32; r += 8) {
        const int n = n0 + r;
        const float w = tile[tx][r];
        const size_t o = (size_t)n * KTOT + k0 + tx;
        Wt[o]  = __float2bfloat16(w);
        Wta[o] = __float2bfloat16(fabsf(w));
    }
}

// ---------------------------------------------------------------------------
// Contention-free grid barrier: per-block arrival flag on its own cache line,
// block 0 checks all 256 in parallel (one flag per thread), then writes 8
// release lines; others poll their leaf release line. Monotonic generation,
// no resets, no RMW in the hot path. Ordering by s_waitcnt(0) before signal.
// ---------------------------------------------------------------------------
__device__ __forceinline__ void gbar(unsigned* bar, unsigned gen,
                                     int bid, int tid) {
    __builtin_amdgcn_s_waitcnt(0);   // this wave's data stores have completed
    __syncthreads();                 // whole block done (each wave waited)
    if (bid == 0) {
        if (tid != 0) {
            while (__hip_atomic_load(&bar[ARV(tid)], __ATOMIC_RELAXED,
                                     __HIP_MEMORY_SCOPE_AGENT) < gen)
                __builtin_amdgcn_s_sleep(1);
        }
        __syncthreads();             // all arrivals observed
        if (tid < 8)
            __hip_atomic_store(&bar[REL(tid)], gen, __ATOMIC_RELAXED,
                               __HIP_MEMORY_SCOPE_AGENT);
    } else {
        if (tid == 0) {
            __hip_atomic_store(&bar[ARV(bid)], gen, __ATOMIC_RELAXED,
                               __HIP_MEMORY_SCOPE_AGENT);
            while (__hip_atomic_load(&bar[REL(bid & 7)], __ATOMIC_RELAXED,
                                     __HIP_MEMORY_SCOPE_AGENT) < gen)
                __builtin_amdgcn_s_sleep(4);
        }
        asm volatile("" ::: "memory");
    }
    __syncthreads();
}

// ---------------------------------------------------------------------------
// One GEMM phase for one wave: prefetch ALL 16 A-fragments (hides the
// coherent-load latency once), then fully-unrolled W-load + MFMA stream.
// ---------------------------------------------------------------------------
__device__ __forceinline__ void gemm_phase(
    const hbf* __restrict__ aptr, bool coh,
    const hbf* const wp[4], int lane, float red[4][64][4])
{
    bf16x8 af[16];
#pragma unroll
    for (int i = 0; i < 16; ++i)
        af[i] = loadA16(aptr + 32 * i, coh);

    f32x4 a0{0,0,0,0}, a1{0,0,0,0}, a2{0,0,0,0}, a3{0,0,0,0};
#pragma unroll
    for (int kk16 = 0; kk16 < 16; ++kk16) {
        const int kk = kk16 * 32;
        const bf16x8 w0 = *(const bf16x8*)(wp[0] + kk);
        const bf16x8 w1 = *(const bf16x8*)(wp[1] + kk);
        const bf16x8 w2 = *(const bf16x8*)(wp[2] + kk);
        const bf16x8 w3 = *(const bf16x8*)(wp[3] + kk);
        a0 = __builtin_amdgcn_mfma_f32_16x16x32_bf16(af[kk16], w0, a0, 0, 0, 0);
        a1 = __builtin_amdgcn_mfma_f32_16x16x32_bf16(af[kk16], w1, a1, 0, 0, 0);
        a2 = __builtin_amdgcn_mfma_f32_16x16x32_bf16(af[kk16], w2, a2, 0, 0, 0);
        a3 = __builtin_amdgcn_mfma_f32_16x16x32_bf16(af[kk16], w3, a3, 0, 0, 0);
    }
    *((f32x4*)&red[0][lane][0]) = a0;
    *((f32x4*)&red[1][lane][0]) = a1;
    *((f32x4*)&red[2][lane][0]) = a2;
    *((f32x4*)&red[3][lane][0]) = a3;
}

// ---------------------------------------------------------------------------
// Cell phase: one thread per (m, j); c-state in registers, bias hoisted.
// ---------------------------------------------------------------------------
__device__ __forceinline__ void cell_phase(
    float red[4][4][64][4], const float* __restrict__ bs,  // bs[4] per thread
    int idx, int ll, int rr,
    float& cl_r, float& cu_r,
    hbf* __restrict__ Hco, hbf* __restrict__ Hro,
    float* __restrict__ hl, float* __restrict__ hu, bool writeF)
{
    float gl[4], gu[4];
#pragma unroll
    for (int g = 0; g < 4; ++g) {
        const float C = red[0][g][ll][rr] + red[2][g][ll][rr];
        const float R = red[1][g][ll][rr] + red[3][g][ll][rr];
        gl[g] = C - R + bs[g];
        gu[g] = C + R + bs[g];
    }

    const float il = fsig(gl[0]), iu = fsig(gu[0]);
    const float fl = fsig(gl[1]), fu = fsig(gu[1]);
    const float ggl = ftanh(gl[2]), ggu = ftanh(gu[2]);
    const float ol = fsig(gl[3]), ou = fsig(gu[3]);

    float fcl, fcu, igl, igu;
    imulf_(fl, fu, cl_r, cu_r, fcl, fcu);
    imulf_(il, iu, ggl, ggu, igl, igu);
    const float ncl = fcl + igl, ncu = fcu + igu;
    cl_r = ncl; cu_r = ncu;

    float nhl, nhu;
    imulf_(ol, ou, ftanh(ncl), ftanh(ncu), nhl, nhu);
    storeH(&Hco[idx], 0.5f * (nhl + nhu));
    storeH(&Hro[idx], 0.5f * (nhu - nhl));
    if (writeF) {
        hl[idx] = nhl;
        hu[idx] = nhu;
    }
}

// ---------------------------------------------------------------------------
// Persistent LSTM, physical-XCD-aware tile assignment (kept from R6),
// deep-prefetch GEMM + flag-array barrier (new).
// ---------------------------------------------------------------------------
__global__ __launch_bounds__(256, 1) void lstm_persistent(
    const hbf* __restrict__ Xc, const hbf* __restrict__ Xr,
    const hbf* __restrict__ Wt0, const hbf* __restrict__ Wt0a,
    const hbf* __restrict__ Wt1, const hbf* __restrict__ Wt1a,
    const float* __restrict__ b0, const float* __restrict__ b1,
    hbf* __restrict__ H0c0, hbf* __restrict__ H0r0,
    hbf* __restrict__ H0c1, hbf* __restrict__ H0r1,
    hbf* __restrict__ H1c0, hbf* __restrict__ H1r0,
    hbf* __restrict__ H1c1, hbf* __restrict__ H1r1,
    float* __restrict__ h1l, float* __restrict__ h1u,
    unsigned* __restrict__ bar)
{
    const int tid  = threadIdx.x;
    const int bid  = blockIdx.x;

    __shared__ unsigned s_tile;
    __shared__ float red[4][4][64][4];    // 16 KB

    // ---- physical-XCD registration ----
    if (tid == 0) {
        unsigned xcc;
        asm volatile("s_getreg_b32 %0, hwreg(HW_REG_XCC_ID)" : "=s"(xcc));
        xcc &= 7u;
        const unsigned slot = __hip_atomic_fetch_add(
            &bar[TKT(xcc)], 1u, __ATOMIC_RELAXED, __HIP_MEMORY_SCOPE_AGENT);
        s_tile = (xcc << 16) | slot;
    }
    unsigned gen = 1;
    gbar(bar, gen, bid, tid);             // all registrations done
    if (tid == 0) {
        const unsigned xcc = s_tile >> 16, slot = s_tile & 0xffffu;
        unsigned base = 0;
        for (unsigned y = 0; y < xcc; ++y)
            base += __hip_atomic_load(&bar[TKT(y)], __ATOMIC_RELAXED,
                                      __HIP_MEMORY_SCOPE_AGENT);
        s_tile = base + slot;             // unique in [0, 256)
    }
    __syncthreads();

    const unsigned tile = s_tile;
    const int j0 = (int)(tile >> 3) * 16;     // same-XCD blocks share j-slices
    const int m0 = (int)(tile & 7) * 16;

    const int w    = tid >> 6;
    const int lane = tid & 63;
    const int op   = w & 1;               // 0 center, 1 radius
    const int ks   = w >> 1;              // K half
    const int rc   = lane & 15;
    const int gk   = lane >> 4;

    const hbf* WbL0 = op ? Wt0a : Wt0;
    const hbf* WbL1 = op ? Wt1a : Wt1;
    const hbf* wp0[4];
    const hbf* wp1[4];
#pragma unroll
    for (int g = 0; g < 4; ++g) {
        const size_t row = (size_t)(g * HID2 + j0 + rc) * KTOT + ks * KH + 8 * gk;
        wp0[g] = WbL0 + row;
        wp1[g] = WbL1 + row;
    }

    hbf* H0cb[2] = {H0c0, H0c1};
    hbf* H0rb[2] = {H0r0, H0r1};
    hbf* H1cb[2] = {H1c0, H1c1};
    hbf* H1rb[2] = {H1r0, H1r1};

    const int arow_off = (m0 + rc) * HID + 8 * gk;

    // per-thread cell constants (fixed tile binding for the whole run)
    const int cm  = tid >> 4;             // m within tile
    const int cj  = tid & 15;             // j within tile
    const int ll  = ((cm >> 2) << 4) | cj;
    const int rr  = cm & 3;
    const int idx = (m0 + cm) * HID2 + j0 + cj;
    float bs0[4], bs1[4];
#pragma unroll
    for (int g = 0; g < 4; ++g) {
        bs0[g] = b0[g * HID2 + j0 + cj];
        bs1[g] = b1[g * HID2 + j0 + cj];
    }

    float c0l_r = 0.f, c0u_r = 0.f, c1l_r = 0.f, c1u_r = 0.f;

    for (int t = 0; t < NF; ++t) {
        const int rd = t & 1, wr2 = rd ^ 1;

        // ---- layer 0: x = X[t] (plain cached), h = H0[rd] (coherent) ----
        {
            const hbf* Ab;
            bool coh;
            if (ks == 0) {
                Ab = (op ? Xr : Xc) + (size_t)t * BATCH * HID;
                coh = false;
            } else {
                Ab = op ? H0rb[rd] : H0cb[rd];
                coh = true;
            }
            gemm_phase(Ab + arow_off, coh, wp0, lane, red[w]);
        }
        __syncthreads();
        cell_phase(red, bs0, idx, ll, rr, c0l_r, c0u_r,
                   H0cb[wr2], H0rb[wr2], nullptr, nullptr, false);
        gbar(bar, ++gen, bid, tid);

        // ---- layer 1: x = H0[wr2], h = H1[rd] (both coherent) ----
        {
            const hbf* Ab;
            if (ks == 0)
                Ab = op ? H0rb[wr2] : H0cb[wr2];
            else
                Ab = op ? H1rb[rd] : H1cb[rd];
            gemm_phase(Ab + arow_off, true, wp1, lane, red[w]);
        }
        __syncthreads();
        cell_phase(red, bs1, idx, ll, rr, c1l_r, c1u_r,
                   H1cb[wr2], H1rb[wr2], h1l, h1u, t == NF - 1);
        gbar(bar, ++gen, bid, tid);
    }
}

// ---------------------------------------------------------------------------
// Final 512 -> 10 interval linear
// ---------------------------------------------------------------------------
__global__ __launch_bounds__(64) void final_kernel(
    const float* __restrict__ h1l, const float* __restrict__ h1u,
    const float* __restrict__ w, const float* __restrict__ bias,
    float* __restrict__ out)
{
    const int b = blockIdx.x;
    const int j = threadIdx.x;
    if (j < NOUT) {
        float oc = bias[j], orr = 0.f;
        for (int i = 0; i < HID2; ++i) {
            const float lo = h1l[(size_t)b * HID2 + i];
            const float hi = h1u[(size_t)b * HID2 + i];
            const float wv = w[i * NOUT + j];
            oc  = fmaf(0.5f * (lo + hi), wv, oc);
            orr = fmaf(0.5f * (hi - lo), fabsf(wv), orr);
        }
        out[b * NOUT + j] = oc - orr;
        out[BATCH * NOUT + b * NOUT + j] = oc + orr;
    }
}

// ---------------------------------------------------------------------------
extern "C" void kernel_launch(void* const* d_in, const int* in_sizes, int n_in,
                              void* d_out, int out_size, void* d_ws, size_t ws_size,
                              hipStream_t stream)
{
    const float* input_lb = (const float*)d_in[0];
    const float* input_ub = (const float*)d_in[1];
    const float* mtx1     = (const float*)d_in[2];
    const float* mtx2     = (const float*)d_in[3];
    const float* lin1_w   = (const float*)d_in[4];
    const float* lin1_b   = (const float*)d_in[5];
    const float* w_ih0    = (const float*)d_in[6];
    const float* w_hh0    = (const float*)d_in[7];
    const float* b0       = (const float*)d_in[8];
    const float* w_ih1    = (const float*)d_in[9];
    const float* w_hh1    = (const float*)d_in[10];
    const float* b1       = (const float*)d_in[11];
    const float* lin2_w   = (const float*)d_in[12];
    const float* lin2_b   = (const float*)d_in[13];
    float* out = (float*)d_out;

    char* ws = (char*)d_ws;
    size_t off = 0;
    hbf* Xc = (hbf*)(ws + off); off += (size_t)NF * BATCH * HID * 2;
    hbf* Xr = (hbf*)(ws + off); off += (size_t)NF * BATCH * HID * 2;
    hbf* Wt0  = (hbf*)(ws + off); off += (size_t)G4 * KTOT * 2;
    hbf* Wt0a = (hbf*)(ws + off); off += (size_t)G4 * KTOT * 2;
    hbf* Wt1  = (hbf*)(ws + off); off += (size_t)G4 * KTOT * 2;
    hbf* Wt1a = (hbf*)(ws + off); off += (size_t)G4 * KTOT * 2;

    // zeroed region: H ping-pong (bf16) + barrier words
    char* zero_base = ws + off;
    const size_t HSZ = (size_t)BATCH * HID2;
    hbf* H0c[2]; hbf* H0r[2]; hbf* H1c[2]; hbf* H1r[2];
    for (int i = 0; i < 2; ++i) {
        H0c[i] = (hbf*)(ws + off); off += HSZ * 2;
        H0r[i] = (hbf*)(ws + off); off += HSZ * 2;
        H1c[i] = (hbf*)(ws + off); off += HSZ * 2;
        H1r[i] = (hbf*)(ws + off); off += HSZ * 2;
    }
    unsigned* bar = (unsigned*)(ws + off); off += (size_t)BAR_WORDS * 4;
    const size_t zero_bytes = (size_t)((ws + off) - zero_base);
    float* h1l = (float*)(ws + off); off += HSZ * 4;
    float* h1u = (float*)(ws + off); off += HSZ * 4;

    hipMemsetAsync(zero_base, 0, zero_bytes, stream);

    {
        const dim3 pgrid(G4 / 32, KTOT / 32);
        prep_weights_kernel<<<pgrid, 256, 0, stream>>>(w_ih0, w_hh0, Wt0, Wt0a);
        prep_weights_kernel<<<pgrid, 256, 0, stream>>>(w_ih1, w_hh1, Wt1, Wt1a);
    }

    frontend_kernel<<<(BATCH * NF) / 8, 512, 0, stream>>>(
        input_lb, input_ub, mtx1, mtx2, lin1_w, lin1_b, Xc, Xr);

    lstm_persistent<<<NBLK, 256, 0, stream>>>(
        Xc, Xr, Wt0, Wt0a, Wt1, Wt1a, b0, b1,
        H0c[0], H0r[0], H0c[1], H0r[1],
        H1c[0], H1r[0], H1c[1], H1r[1],
        h1l, h1u, bar);

    final_kernel<<<BATCH, 64, 0, stream>>>(h1l, h1u, lin2_w, lin2_b, out);
}

// Round 8
// 4907.929 us; speedup vs baseline: 3.1765x; 1.4734x over previous
//
#include <hip/hip_runtime.h>
#include <hip/hip_bf16.h>
#include <math.h>

#define BATCH 128
#define LEN   64000
#define FS    256
#define STEPS 200
#define NFILT 64
#define HID   512
#define HID2  512
#define NOUT  10
#define NF    320        // timesteps
#define G4    2048       // 4*HID2
#define KTOT  1024
#define NBLK  256        // persistent grid

typedef __bf16  bf16x8 __attribute__((ext_vector_type(8)));
typedef float   f32x4  __attribute__((ext_vector_type(4)));
typedef __hip_bfloat16 hbf;

// barrier-word layout (unsigned words, 64B-line stride 16)
#define ARV(b)  (128 + (b) * 16)        // 256 arrive flags
#define REL(i)  (128 + 4096 + (i) * 16) // 8 release flags
#define BAR_WORDS (128 + 4096 + 128)

// ---------------------------------------------------------------------------
// Fast transcendentals
// ---------------------------------------------------------------------------
__device__ __forceinline__ float fsig(float x) {
    return 1.f / (1.f + __expf(-x));
}
__device__ __forceinline__ float ftanh(float x) {
    return 1.f - 2.f / (__expf(2.f * x) + 1.f);
}
__device__ __forceinline__ void imulf_(float al, float au, float bl, float bu,
                                       float& lo, float& hi) {
    const float p1 = al * bl, p2 = al * bu, p3 = au * bl, p4 = au * bu;
    lo = fminf(fminf(p1, p2), fminf(p3, p4));
    hi = fmaxf(fmaxf(p1, p2), fmaxf(p3, p4));
}

// ---------------------------------------------------------------------------
// Device-coherent H access (sc-bit per-access coherence, no cache flushes).
// ---------------------------------------------------------------------------
__device__ __forceinline__ bf16x8 loadA16(const hbf* p, bool coh) {
    if (coh) {
        union { unsigned long long u[2]; bf16x8 v; } t;
        unsigned long long* q = (unsigned long long*)p;
        t.u[0] = __hip_atomic_load(q,     __ATOMIC_RELAXED, __HIP_MEMORY_SCOPE_AGENT);
        t.u[1] = __hip_atomic_load(q + 1, __ATOMIC_RELAXED, __HIP_MEMORY_SCOPE_AGENT);
        return t.v;
    }
    return *(const bf16x8*)p;
}
__device__ __forceinline__ void storeH(hbf* p, float v) {
    const __hip_bfloat16 h = __float2bfloat16(v);
    __hip_atomic_store((unsigned short*)p, *(const unsigned short*)&h,
                       __ATOMIC_RELAXED, __HIP_MEMORY_SCOPE_AGENT);
}

// ---------------------------------------------------------------------------
// Frontend: 8 (b,f)-rows per block, one wave per row. Writes bf16 c/r
// with layout [t][b][512].
// ---------------------------------------------------------------------------
__global__ __launch_bounds__(512) void frontend_kernel(
    const float* __restrict__ lb, const float* __restrict__ ub,
    const float* __restrict__ mtx1, const float* __restrict__ mtx2,
    const float* __restrict__ lin1_w, const float* __restrict__ lin1_b,
    hbf* __restrict__ Xc, hbf* __restrict__ Xr)
{
    const int tid  = threadIdx.x;
    const int r    = tid >> 6;
    const int lane = tid & 63;
    const int rowid = blockIdx.x * 8 + r;
    const int f = rowid % NF;
    const int b = rowid / NF;

    __shared__ float sc[8][FS], sr[8][FS];
    __shared__ float s2c[8][FS + 2], s2r[8][FS + 2];
    __shared__ float s3c[8][NFILT], s3r[8][NFILT];

    for (int i = lane; i < FS; i += 64) {
        const int pos = f * STEPS + i;
        float l = 0.f, u = 0.f;
        if (pos < LEN) {
            l = lb[(size_t)b * LEN + pos];
            u = ub[(size_t)b * LEN + pos];
        }
        sc[r][i] = 0.5f * (l + u);
        sr[r][i] = 0.5f * (u - l);
    }
    __syncthreads();

    for (int j = lane; j < FS + 2; j += 64) {
        float oc = 0.f, orr = 0.f;
#pragma unroll 4
        for (int i = 0; i < FS; ++i) {
            const float w = mtx1[i * (FS + 2) + j];
            oc  = fmaf(sc[r][i], w, oc);
            orr = fmaf(sr[r][i], fabsf(w), orr);
        }
        const float l1l = oc - orr, l1u = oc + orr;
        const float a = l1l * l1l, bb = l1u * l1u;
        const float squ = fmaxf(a, bb);
        const float sql = (l1l <= 0.f && l1u >= 0.f) ? 0.f : fminf(a, bb);
        s2c[r][j] = 0.5f * (sql + squ);
        s2r[r][j] = 0.5f * (squ - sql);
    }
    __syncthreads();

    {
        const int j = lane;
        float oc = 1e-10f, orr = 0.f;
#pragma unroll 4
        for (int i = 0; i < FS + 2; ++i) {
            const float w = mtx2[i * NFILT + j];
            oc  = fmaf(s2c[r][i], w, oc);
            orr = fmaf(s2r[r][i], fabsf(w), orr);
        }
        const float lgl = logf(oc - orr);
        const float lgu = logf(oc + orr);
        s3c[r][j] = 0.5f * (lgl + lgu);
        s3r[r][j] = 0.5f * (lgu - lgl);
    }
    __syncthreads();

    for (int j = lane; j < HID; j += 64) {
        float oc = lin1_b[j], orr = 0.f;
#pragma unroll 4
        for (int i = 0; i < NFILT; ++i) {
            const float w = lin1_w[i * HID + j];
            oc  = fmaf(s3c[r][i], w, oc);
            orr = fmaf(s3r[r][i], fabsf(w), orr);
        }
        const float n1l = oc - orr, n1u = oc + orr;
        const float rl = fmaxf(n1l, 0.f), ru = fmaxf(n1u, 0.f);
        const size_t o = ((size_t)f * BATCH + b) * HID + j;
        Xc[o] = __float2bfloat16(0.5f * (rl + ru));
        Xr[o] = __float2bfloat16(0.5f * (ru - rl));
    }
}

// ---------------------------------------------------------------------------
// Weight prep: Wt[n=2048][k=1024] bf16; k<512 from w_ih, else w_hh.
// ---------------------------------------------------------------------------
__global__ __launch_bounds__(256) void prep_weights_kernel(
    const float* __restrict__ wih, const float* __restrict__ whh,
    hbf* __restrict__ Wt)
{
    __shared__ float tile[32][33];
    const int n0 = blockIdx.x * 32;
    const int k0 = blockIdx.y * 32;
    const int tx = threadIdx.x & 31;
    const int ty = threadIdx.x >> 5;

    for (int r = ty; r < 32; r += 8) {
        const int k = k0 + r;
        const float* src = (k < HID) ? (wih + (size_t)k * G4)
                                     : (whh + (size_t)(k - HID) * G4);
        tile[r][tx] = src[n0 + tx];
    }
    __syncthreads();
    for (int r = ty; r < 32; r += 8) {
        const int n = n0 + r;
        Wt[(size_t)n * KTOT + k0 + tx] = __float2bfloat16(tile[tx][r]);
    }
}

// ---------------------------------------------------------------------------
// Contention-free grid barrier (proven in R7): per-block arrival flag on its
// own line; block 0 polls all in parallel, writes 8 release lines; others
// poll their leaf line. Monotonic generation, no RMW in the hot path.
// ---------------------------------------------------------------------------
__device__ __forceinline__ void gbar(unsigned* bar, unsigned gen,
                                     int bid, int tid) {
    __builtin_amdgcn_s_waitcnt(0);   // this wave's data stores have completed
    __syncthreads();                 // whole block done
    if (bid == 0) {
        if (tid != 0) {
            while (__hip_atomic_load(&bar[ARV(tid)], __ATOMIC_RELAXED,
                                     __HIP_MEMORY_SCOPE_AGENT) < gen)
                __builtin_amdgcn_s_sleep(1);
        }
        __syncthreads();             // all arrivals observed
        if (tid < 8)
            __hip_atomic_store(&bar[REL(tid)], gen, __ATOMIC_RELAXED,
                               __HIP_MEMORY_SCOPE_AGENT);
    } else {
        if (tid == 0) {
            __hip_atomic_store(&bar[ARV(bid)], gen, __ATOMIC_RELAXED,
                               __HIP_MEMORY_SCOPE_AGENT);
            while (__hip_atomic_load(&bar[REL(bid & 7)], __ATOMIC_RELAXED,
                                     __HIP_MEMORY_SCOPE_AGENT) < gen)
                __builtin_amdgcn_s_sleep(4);
        }
        asm volatile("" ::: "memory");
    }
    __syncthreads();
}

// ---------------------------------------------------------------------------
// Cell math for one (m, j) element from C/R gate sums.
// ---------------------------------------------------------------------------
__device__ __forceinline__ void cell_elem(
    const float C[4], const float R[4], const float bs[4],
    float& cl_r, float& cu_r, float& nhl, float& nhu)
{
    float gl[4], gu[4];
#pragma unroll
    for (int g = 0; g < 4; ++g) {
        gl[g] = C[g] - R[g] + bs[g];
        gu[g] = C[g] + R[g] + bs[g];
    }
    const float il = fsig(gl[0]), iu = fsig(gu[0]);
    const float fl = fsig(gl[1]), fu = fsig(gu[1]);
    const float ggl = ftanh(gl[2]), ggu = ftanh(gu[2]);
    const float ol = fsig(gl[3]), ou = fsig(gu[3]);

    float fcl, fcu, igl, igu;
    imulf_(fl, fu, cl_r, cu_r, fcl, fcu);
    imulf_(il, iu, ggl, ggu, igl, igu);
    const float ncl = fcl + igl, ncu = fcu + igu;
    cl_r = ncl; cu_r = ncu;
    imulf_(ol, ou, ftanh(ncl), ftanh(ncu), nhl, nhu);
}

// ---------------------------------------------------------------------------
// Persistent layer-parallel LSTM.
// Blocks 0..127: layer 0; blocks 128..255: layer 1. Each owns a 32m x 16j
// tile of ONE layer; its weight slice (4 gates x 16 cols x 1024 k bf16 =
// 128 KB) is staged into LDS once, fragment-ordered -> zero L2 weight
// traffic in the steady state. |W| is computed on the fly (sign-mask).
// Software pipeline: at super-step s, L0 computes H0[s], L1 computes
// H1[s-1] -> ONE grid barrier per timestep (321 total).
// Waves: op = w&1 (center/radius), mh = w>>1 (m-half, 16 rows). Full K=1024
// per wave; C/R combine via 16 KB LDS red. c-state in registers.
// ---------------------------------------------------------------------------
__global__ __launch_bounds__(256, 1) void lstm_persistent(
    const hbf* __restrict__ Xc, const hbf* __restrict__ Xr,
    const hbf* __restrict__ Wt0, const hbf* __restrict__ Wt1,
    const float* __restrict__ b0, const float* __restrict__ b1,
    hbf* __restrict__ H0c0, hbf* __restrict__ H0r0,
    hbf* __restrict__ H0c1, hbf* __restrict__ H0r1,
    hbf* __restrict__ H1c0, hbf* __restrict__ H1r0,
    hbf* __restrict__ H1c1, hbf* __restrict__ H1r1,
    float* __restrict__ h1l, float* __restrict__ h1u,
    unsigned* __restrict__ bar)
{
    const int tid   = threadIdx.x;
    const int bid   = blockIdx.x;
    const int layer = bid >> 7;           // 0 or 1
    const int sub   = bid & 127;
    const int m0    = (sub >> 5) * 32;    // 4 m-tiles
    const int j0    = (sub & 31) * 16;    // 32 j-tiles

    __shared__ hbf   Wlds[4 * 32 * 64 * 8];   // 128 KB, [g][kk][lane][8]
    __shared__ float red[4][4][64][4];        // 16 KB

    // ---- stage this block's weight slice into LDS (once) ----
    {
        const hbf* Wt = layer ? Wt1 : Wt0;
        for (int c = tid; c < 8192; c += 256) {
            const int g  = c >> 11;
            const int kk = (c >> 6) & 31;
            const int l6 = c & 63;
            const int n  = g * HID2 + j0 + (l6 & 15);
            const int k  = kk * 32 + (l6 >> 4) * 8;
            *(ulonglong2*)&Wlds[(size_t)c * 8] =
                *(const ulonglong2*)(Wt + (size_t)n * KTOT + k);
        }
    }

    const int w    = tid >> 6;
    const int lane = tid & 63;
    const int op   = w & 1;               // 0 center, 1 radius
    const int mh   = w >> 1;              // m-half
    const int rc   = lane & 15;
    const int gk   = lane >> 4;
    const unsigned absmask = op ? 0x7FFF7FFFu : 0xFFFFFFFFu;

    const int arow = m0 + mh * 16 + rc;
    const int aoff = arow * 512 + 8 * gk; // offset within a [.][512] buffer

    hbf* H0cb[2] = {H0c0, H0c1};
    hbf* H0rb[2] = {H0r0, H0r1};
    hbf* H1cb[2] = {H1c0, H1c1};
    hbf* H1rb[2] = {H1r0, H1r1};

    // cell-phase per-thread constants (2 elements: mh=0 and mh=1 copies)
    const int mm  = tid >> 4;             // 0..15
    const int cj  = tid & 15;
    const int ll  = ((mm >> 2) << 4) | cj;
    const int rr  = mm & 3;
    const int idx0 = (m0 + mm) * HID2 + j0 + cj;
    const int idx1 = idx0 + 16 * HID2;
    const float* bias = layer ? b1 : b0;
    float bs[4];
#pragma unroll
    for (int g = 0; g < 4; ++g)
        bs[g] = bias[g * HID2 + j0 + cj];

    float cAl = 0.f, cAu = 0.f, cBl = 0.f, cBu = 0.f;

    __syncthreads();                      // Wlds ready

    unsigned gen = 0;
    for (int s = 0; s <= NF; ++s) {
        const int wrp = s & 1, rdp = wrp ^ 1;
        const bool active = layer == 0 ? (s < NF) : (s > 0);

        if (active) {
            const int t = layer == 0 ? s : s - 1;
            const hbf* ax;  bool cohx;
            const hbf* ah;
            if (layer == 0) {
                ax = (op ? Xr : Xc) + (size_t)t * BATCH * HID + aoff;
                cohx = false;
                ah = (op ? H0rb[rdp] : H0cb[rdp]) + aoff;
            } else {
                ax = (op ? H0rb[rdp] : H0cb[rdp]) + aoff;
                cohx = true;
                ah = (op ? H1rb[rdp] : H1cb[rdp]) + aoff;
            }

            // prefetch all 32 A-fragments (one exposed latency)
            bf16x8 af[32];
#pragma unroll
            for (int i = 0; i < 16; ++i) af[i] = loadA16(ax + 32 * i, cohx);
#pragma unroll
            for (int i = 0; i < 16; ++i) af[16 + i] = loadA16(ah + 32 * i, true);

            f32x4 acc[4] = {f32x4{0,0,0,0}, f32x4{0,0,0,0},
                            f32x4{0,0,0,0}, f32x4{0,0,0,0}};
#pragma unroll
            for (int kk = 0; kk < 32; ++kk) {
                const bf16x8 a = af[kk];
#pragma unroll
                for (int g = 0; g < 4; ++g) {
                    union { bf16x8 v; unsigned u[4]; } t2;
                    t2.v = *(const bf16x8*)&Wlds[(size_t)(((g << 5) | kk) * 64 + lane) * 8];
                    t2.u[0] &= absmask; t2.u[1] &= absmask;
                    t2.u[2] &= absmask; t2.u[3] &= absmask;
                    acc[g] = __builtin_amdgcn_mfma_f32_16x16x32_bf16(a, t2.v, acc[g], 0, 0, 0);
                }
            }
#pragma unroll
            for (int g = 0; g < 4; ++g)
                *((f32x4*)&red[w][g][lane][0]) = acc[g];
        }
        __syncthreads();

        if (active) {
            float C0[4], R0[4], C1[4], R1[4];
#pragma unroll
            for (int g = 0; g < 4; ++g) {
                C0[g] = red[0][g][ll][rr];
                R0[g] = red[1][g][ll][rr];
                C1[g] = red[2][g][ll][rr];
                R1[g] = red[3][g][ll][rr];
            }
            hbf* Hco = layer ? H1cb[wrp] : H0cb[wrp];
            hbf* Hro = layer ? H1rb[wrp] : H0rb[wrp];
            const bool writeF = (layer == 1) && (s == NF);

            float nhl, nhu;
            cell_elem(C0, R0, bs, cAl, cAu, nhl, nhu);
            storeH(&Hco[idx0], 0.5f * (nhl + nhu));
            storeH(&Hro[idx0], 0.5f * (nhu - nhl));
            if (writeF) { h1l[idx0] = nhl; h1u[idx0] = nhu; }

            cell_elem(C1, R1, bs, cBl, cBu, nhl, nhu);
            storeH(&Hco[idx1], 0.5f * (nhl + nhu));
            storeH(&Hro[idx1], 0.5f * (nhu - nhl));
            if (writeF) { h1l[idx1] = nhl; h1u[idx1] = nhu; }
        }
        gbar(bar, ++gen, bid, tid);
    }
}

// ---------------------------------------------------------------------------
// Final 512 -> 10 interval linear
// ---------------------------------------------------------------------------
__global__ __launch_bounds__(64) void final_kernel(
    const float* __restrict__ h1l, const float* __restrict__ h1u,
    const float* __restrict__ w, const float* __restrict__ bias,
    float* __restrict__ out)
{
    const int b = blockIdx.x;
    const int j = threadIdx.x;
    if (j < NOUT) {
        float oc = bias[j], orr = 0.f;
        for (int i = 0; i < HID2; ++i) {
            const float lo = h1l[(size_t)b * HID2 + i];
            const float hi = h1u[(size_t)b * HID2 + i];
            const float wv = w[i * NOUT + j];
            oc  = fmaf(0.5f * (lo + hi), wv, oc);
            orr = fmaf(0.5f * (hi - lo), fabsf(wv), orr);
        }
        out[b * NOUT + j] = oc - orr;
        out[BATCH * NOUT + b * NOUT + j] = oc + orr;
    }
}

// ---------------------------------------------------------------------------
extern "C" void kernel_launch(void* const* d_in, const int* in_sizes, int n_in,
                              void* d_out, int out_size, void* d_ws, size_t ws_size,
                              hipStream_t stream)
{
    const float* input_lb = (const float*)d_in[0];
    const float* input_ub = (const float*)d_in[1];
    const float* mtx1     = (const float*)d_in[2];
    const float* mtx2     = (const float*)d_in[3];
    const float* lin1_w   = (const float*)d_in[4];
    const float* lin1_b   = (const float*)d_in[5];
    const float* w_ih0    = (const float*)d_in[6];
    const float* w_hh0    = (const float*)d_in[7];
    const float* b0       = (const float*)d_in[8];
    const float* w_ih1    = (const float*)d_in[9];
    const float* w_hh1    = (const float*)d_in[10];
    const float* b1       = (const float*)d_in[11];
    const float* lin2_w   = (const float*)d_in[12];
    const float* lin2_b   = (const float*)d_in[13];
    float* out = (float*)d_out;

    char* ws = (char*)d_ws;
    size_t off = 0;
    hbf* Xc = (hbf*)(ws + off); off += (size_t)NF * BATCH * HID * 2;
    hbf* Xr = (hbf*)(ws + off); off += (size_t)NF * BATCH * HID * 2;
    hbf* Wt0 = (hbf*)(ws + off); off += (size_t)G4 * KTOT * 2;
    hbf* Wt1 = (hbf*)(ws + off); off += (size_t)G4 * KTOT * 2;

    // zeroed region: H ping-pong (bf16) + barrier words
    char* zero_base = ws + off;
    const size_t HSZ = (size_t)BATCH * HID2;
    hbf* H0c[2]; hbf* H0r[2]; hbf* H1c[2]; hbf* H1r[2];
    for (int i = 0; i < 2; ++i) {
        H0c[i] = (hbf*)(ws + off); off += HSZ * 2;
        H0r[i] = (hbf*)(ws + off); off += HSZ * 2;
        H1c[i] = (hbf*)(ws + off); off += HSZ * 2;
        H1r[i] = (hbf*)(ws + off); off += HSZ * 2;
    }
    unsigned* bar = (unsigned*)(ws + off); off += (size_t)BAR_WORDS * 4;
    const size_t zero_bytes = (size_t)((ws + off) - zero_base);
    float* h1l = (float*)(ws + off); off += HSZ * 4;
    float* h1u = (float*)(ws + off); off += HSZ * 4;

    hipMemsetAsync(zero_base, 0, zero_bytes, stream);

    {
        const dim3 pgrid(G4 / 32, KTOT / 32);
        prep_weights_kernel<<<pgrid, 256, 0, stream>>>(w_ih0, w_hh0, Wt0);
        prep_weights_kernel<<<pgrid, 256, 0, stream>>>(w_ih1, w_hh1, Wt1);
    }

    frontend_kernel<<<(BATCH * NF) / 8, 512, 0, stream>>>(
        input_lb, input_ub, mtx1, mtx2, lin1_w, lin1_b, Xc, Xr);

    lstm_persistent<<<NBLK, 256, 0, stream>>>(
        Xc, Xr, Wt0, Wt1, b0, b1,
        H0c[0], H0r[0], H0c[1], H0r[1],
        H1c[0], H1r[0], H1c[1], H1r[1],
        h1l, h1u, bar);

    final_kernel<<<BATCH, 64, 0, stream>>>(h1l, h1u, lin2_w, lin2_b, out);
}

// Round 9
// 4529.399 us; speedup vs baseline: 3.4420x; 1.0836x over previous
//
#include <hip/hip_runtime.h>
#include <hip/hip_bf16.h>
#include <math.h>

#define BATCH 128
#define LEN   64000
#define FS    256
#define STEPS 200
#define NFILT 64
#define HID   512
#define HID2  512
#define NOUT  10
#define NF    320        // timesteps
#define G4    2048       // 4*HID2
#define KTOT  1024
#define NBLK  256        // persistent grid
#define HSLOT (BATCH * HID2)   // elements per H slot (65536)

typedef __bf16  bf16x8 __attribute__((ext_vector_type(8)));
typedef float   f32x4  __attribute__((ext_vector_type(4)));
typedef __hip_bfloat16 hbf;

// ---------------------------------------------------------------------------
// Fast transcendentals
// ---------------------------------------------------------------------------
__device__ __forceinline__ float fsig(float x) {
    return 1.f / (1.f + __expf(-x));
}
__device__ __forceinline__ float ftanh(float x) {
    return 1.f - 2.f / (__expf(2.f * x) + 1.f);
}
__device__ __forceinline__ void imulf_(float al, float au, float bl, float bu,
                                       float& lo, float& hi) {
    const float p1 = al * bl, p2 = al * bu, p3 = au * bl, p4 = au * bu;
    lo = fminf(fminf(p1, p2), fminf(p3, p4));
    hi = fmaxf(fmaxf(p1, p2), fmaxf(p3, p4));
}

// ---------------------------------------------------------------------------
// Device-coherent H access (sc-bit per-access coherence, no cache flushes).
// ---------------------------------------------------------------------------
__device__ __forceinline__ bf16x8 loadA16(const hbf* p, bool coh) {
    if (coh) {
        union { unsigned long long u[2]; bf16x8 v; } t;
        unsigned long long* q = (unsigned long long*)p;
        t.u[0] = __hip_atomic_load(q,     __ATOMIC_RELAXED, __HIP_MEMORY_SCOPE_AGENT);
        t.u[1] = __hip_atomic_load(q + 1, __ATOMIC_RELAXED, __HIP_MEMORY_SCOPE_AGENT);
        return t.v;
    }
    return *(const bf16x8*)p;
}
__device__ __forceinline__ void storeH(hbf* p, float v) {
    const __hip_bfloat16 h = __float2bfloat16(v);
    __hip_atomic_store((unsigned short*)p, *(const unsigned short*)&h,
                       __ATOMIC_RELAXED, __HIP_MEMORY_SCOPE_AGENT);
}

// ---------------------------------------------------------------------------
// Frontend: 8 (b,f)-rows per block, one wave per row. Writes bf16 c/r
// with layout [t][b][512].
// ---------------------------------------------------------------------------
__global__ __launch_bounds__(512) void frontend_kernel(
    const float* __restrict__ lb, const float* __restrict__ ub,
    const float* __restrict__ mtx1, const float* __restrict__ mtx2,
    const float* __restrict__ lin1_w, const float* __restrict__ lin1_b,
    hbf* __restrict__ Xc, hbf* __restrict__ Xr)
{
    const int tid  = threadIdx.x;
    const int r    = tid >> 6;
    const int lane = tid & 63;
    const int rowid = blockIdx.x * 8 + r;
    const int f = rowid % NF;
    const int b = rowid / NF;

    __shared__ float sc[8][FS], sr[8][FS];
    __shared__ float s2c[8][FS + 2], s2r[8][FS + 2];
    __shared__ float s3c[8][NFILT], s3r[8][NFILT];

    for (int i = lane; i < FS; i += 64) {
        const int pos = f * STEPS + i;
        float l = 0.f, u = 0.f;
        if (pos < LEN) {
            l = lb[(size_t)b * LEN + pos];
            u = ub[(size_t)b * LEN + pos];
        }
        sc[r][i] = 0.5f * (l + u);
        sr[r][i] = 0.5f * (u - l);
    }
    __syncthreads();

    for (int j = lane; j < FS + 2; j += 64) {
        float oc = 0.f, orr = 0.f;
#pragma unroll 4
        for (int i = 0; i < FS; ++i) {
            const float w = mtx1[i * (FS + 2) + j];
            oc  = fmaf(sc[r][i], w, oc);
            orr = fmaf(sr[r][i], fabsf(w), orr);
        }
        const float l1l = oc - orr, l1u = oc + orr;
        const float a = l1l * l1l, bb = l1u * l1u;
        const float squ = fmaxf(a, bb);
        const float sql = (l1l <= 0.f && l1u >= 0.f) ? 0.f : fminf(a, bb);
        s2c[r][j] = 0.5f * (sql + squ);
        s2r[r][j] = 0.5f * (squ - sql);
    }
    __syncthreads();

    {
        const int j = lane;
        float oc = 1e-10f, orr = 0.f;
#pragma unroll 4
        for (int i = 0; i < FS + 2; ++i) {
            const float w = mtx2[i * NFILT + j];
            oc  = fmaf(s2c[r][i], w, oc);
            orr = fmaf(s2r[r][i], fabsf(w), orr);
        }
        const float lgl = logf(oc - orr);
        const float lgu = logf(oc + orr);
        s3c[r][j] = 0.5f * (lgl + lgu);
        s3r[r][j] = 0.5f * (lgu - lgl);
    }
    __syncthreads();

    for (int j = lane; j < HID; j += 64) {
        float oc = lin1_b[j], orr = 0.f;
#pragma unroll 4
        for (int i = 0; i < NFILT; ++i) {
            const float w = lin1_w[i * HID + j];
            oc  = fmaf(s3c[r][i], w, oc);
            orr = fmaf(s3r[r][i], fabsf(w), orr);
        }
        const float n1l = oc - orr, n1u = oc + orr;
        const float rl = fmaxf(n1l, 0.f), ru = fmaxf(n1u, 0.f);
        const size_t o = ((size_t)f * BATCH + b) * HID + j;
        Xc[o] = __float2bfloat16(0.5f * (rl + ru));
        Xr[o] = __float2bfloat16(0.5f * (ru - rl));
    }
}

// ---------------------------------------------------------------------------
// Weight prep: Wt[n=2048][k=1024] bf16; k<512 from w_ih, else w_hh.
// ---------------------------------------------------------------------------
__global__ __launch_bounds__(256) void prep_weights_kernel(
    const float* __restrict__ wih, const float* __restrict__ whh,
    hbf* __restrict__ Wt)
{
    __shared__ float tile[32][33];
    const int n0 = blockIdx.x * 32;
    const int k0 = blockIdx.y * 32;
    const int tx = threadIdx.x & 31;
    const int ty = threadIdx.x >> 5;

    for (int r = ty; r < 32; r += 8) {
        const int k = k0 + r;
        const float* src = (k < HID) ? (wih + (size_t)k * G4)
                                     : (whh + (size_t)(k - HID) * G4);
        tile[r][tx] = src[n0 + tx];
    }
    __syncthreads();
    for (int r = ty; r < 32; r += 8) {
        const int n = n0 + r;
        Wt[(size_t)n * KTOT + k0 + tx] = __float2bfloat16(tile[tx][r]);
    }
}

// ---------------------------------------------------------------------------
// Cell math for one (m, j) element from C/R gate sums.
// ---------------------------------------------------------------------------
__device__ __forceinline__ void cell_elem(
    const float C[4], const float R[4], const float bs[4],
    float& cl_r, float& cu_r, float& nhl, float& nhu)
{
    float gl[4], gu[4];
#pragma unroll
    for (int g = 0; g < 4; ++g) {
        gl[g] = C[g] - R[g] + bs[g];
        gu[g] = C[g] + R[g] + bs[g];
    }
    const float il = fsig(gl[0]), iu = fsig(gu[0]);
    const float fl = fsig(gl[1]), fu = fsig(gu[1]);
    const float ggl = ftanh(gl[2]), ggu = ftanh(gu[2]);
    const float ol = fsig(gl[3]), ou = fsig(gu[3]);

    float fcl, fcu, igl, igu;
    imulf_(fl, fu, cl_r, cu_r, fcl, fcu);
    imulf_(il, iu, ggl, ggu, igl, igu);
    const float ncl = fcl + igl, ncu = fcu + igu;
    cl_r = ncl; cu_r = ncu;
    imulf_(ol, ou, ftanh(ncl), ftanh(ncu), nhl, nhu);
}

// ---------------------------------------------------------------------------
// Persistent LSTM, group-decoupled.
// 8 independent groups of 32 blocks: group = (layer, mgrp), mgrp = 32-row
// m-group. Block within group owns a 32m x 16j tile; weight slice (128 KB)
// lives in LDS. Waves = (op, K-half): each W fragment read once per block
// pair of m-halves (2 MFMAs per read); C/R + K-half combine via 16 KB red
// in two passes. Groups sync via per-group 32-flag barriers (no global
// barrier). L0 publishes H0 into a full-history ring (no backpressure);
// L1 groups poll L0's arrival flags (>= t+1) before consuming H0[t].
// ---------------------------------------------------------------------------
__global__ __launch_bounds__(256, 1) void lstm_persistent(
    const hbf* __restrict__ Xc, const hbf* __restrict__ Xr,
    const hbf* __restrict__ Wt0, const hbf* __restrict__ Wt1,
    const float* __restrict__ b0, const float* __restrict__ b1,
    hbf* __restrict__ H0c_ring, hbf* __restrict__ H0r_ring,  // (NF+1) slots
    hbf* __restrict__ H1c0, hbf* __restrict__ H1r0,
    hbf* __restrict__ H1c1, hbf* __restrict__ H1r1,
    float* __restrict__ h1l, float* __restrict__ h1u,
    unsigned* __restrict__ flags)                             // 256 x 64B lines
{
    const int tid   = threadIdx.x;
    const int bid   = blockIdx.x;
    const int layer = bid >> 7;           // 0 or 1
    const int sub   = bid & 127;
    const int mgrp  = sub >> 5;           // 0..3
    const int m0    = mgrp * 32;
    const int j0    = (sub & 31) * 16;
    const int gbase = (layer << 7) + mgrp * 32;  // own group's base bid
    const int l0base = mgrp * 32;                // layer-0 group, same m rows

    __shared__ hbf   Wlds[4 * 32 * 64 * 8];      // 128 KB [g][kk][lane][8]
    __shared__ float red[2][4][2][64][4];        // 16 KB [op][g][mh][lane][reg]

    // ---- stage this block's weight slice into LDS (once) ----
    {
        const hbf* Wt = layer ? Wt1 : Wt0;
        for (int c = tid; c < 8192; c += 256) {
            const int g  = c >> 11;
            const int kk = (c >> 6) & 31;
            const int l6 = c & 63;
            const int n  = g * HID2 + j0 + (l6 & 15);
            const int k  = kk * 32 + (l6 >> 4) * 8;
            *(ulonglong2*)&Wlds[(size_t)c * 8] =
                *(const ulonglong2*)(Wt + (size_t)n * KTOT + k);
        }
    }

    const int w    = tid >> 6;
    const int lane = tid & 63;
    const int op   = w & 1;               // 0 center, 1 radius
    const int ks   = w >> 1;              // 0: x-part (k<512), 1: h-part
    const int rc   = lane & 15;
    const int gk   = lane >> 4;
    const unsigned absmask = op ? 0x7FFF7FFFu : 0xFFFFFFFFu;

    const int aoff0 = (m0 + rc) * 512 + 8 * gk;   // mh=0 row, within a slot
    const int aoff1 = aoff0 + 16 * 512;           // mh=1

    // cell-phase per-thread constants
    const int mm  = tid >> 4;             // 0..15
    const int cj  = tid & 15;
    const int ll  = ((mm >> 2) << 4) | cj;
    const int rr  = mm & 3;
    const int idx0 = (m0 + mm) * HID2 + j0 + cj;
    const int idx1 = idx0 + 16 * HID2;
    const float* bias = layer ? b1 : b0;
    float bs[4];
#pragma unroll
    for (int g = 0; g < 4; ++g)
        bs[g] = bias[g * HID2 + j0 + cj];

    float cAl = 0.f, cAu = 0.f, cBl = 0.f, cBu = 0.f;

    __syncthreads();                      // Wlds ready

    for (int t = 0; t < NF; ++t) {
        // ---- poll: own group done with t-1; (L1) L0 group published H0[t] ----
        if (tid < 64) {
            int fbid, tgt;
            if (tid < 32)      { fbid = gbase + tid;        tgt = t; }
            else if (layer)    { fbid = l0base + (tid - 32); tgt = t + 1; }
            else               { fbid = gbase + (tid - 32);  tgt = t; }
            for (;;) {
                const unsigned v = __hip_atomic_load(&flags[fbid * 16],
                                                     __ATOMIC_RELAXED,
                                                     __HIP_MEMORY_SCOPE_AGENT);
                if (__all((int)v >= tgt)) break;
                __builtin_amdgcn_s_sleep(2);
            }
        }
        __syncthreads();

        // ---- A source for this wave ----
        const hbf* asrc;
        bool coh = true;
        if (ks == 0) {
            if (layer == 0) {
                asrc = (op ? Xr : Xc) + (size_t)t * HSLOT;
                coh = false;
            } else {
                asrc = (op ? H0r_ring : H0c_ring) + (size_t)t * HSLOT;
            }
        } else {
            if (layer == 0) {
                const int pt = (t == 0) ? NF : t - 1;   // slot NF = zeros
                asrc = (op ? H0r_ring : H0c_ring) + (size_t)pt * HSLOT;
            } else {
                const hbf* cb = ((t + 1) & 1) ? H1c1 : H1c0;
                const hbf* rb = ((t + 1) & 1) ? H1r1 : H1r0;
                asrc = op ? rb : cb;
            }
        }

        // ---- prefetch all 32 A-fragments (one exposed latency) ----
        bf16x8 af[32];
#pragma unroll
        for (int i = 0; i < 16; ++i) af[i]      = loadA16(asrc + aoff0 + 32 * i, coh);
#pragma unroll
        for (int i = 0; i < 16; ++i) af[16 + i] = loadA16(asrc + aoff1 + 32 * i, coh);

        // ---- GEMM: K-half, all 4 gates, both m-halves ----
        f32x4 acc[4][2];
#pragma unroll
        for (int g = 0; g < 4; ++g) {
            acc[g][0] = f32x4{0, 0, 0, 0};
            acc[g][1] = f32x4{0, 0, 0, 0};
        }
#pragma unroll
        for (int kk = 0; kk < 16; ++kk) {
#pragma unroll
            for (int g = 0; g < 4; ++g) {
                union { bf16x8 v; unsigned u[4]; } t2;
                t2.v = *(const bf16x8*)
                    &Wlds[(size_t)(((g << 5) | (ks * 16 + kk)) * 64 + lane) * 8];
                t2.u[0] &= absmask; t2.u[1] &= absmask;
                t2.u[2] &= absmask; t2.u[3] &= absmask;
                acc[g][0] = __builtin_amdgcn_mfma_f32_16x16x32_bf16(af[kk],      t2.v, acc[g][0], 0, 0, 0);
                acc[g][1] = __builtin_amdgcn_mfma_f32_16x16x32_bf16(af[16 + kk], t2.v, acc[g][1], 0, 0, 0);
            }
        }

        // ---- combine K-halves through red (2 passes) ----
        if (ks == 0) {
#pragma unroll
            for (int g = 0; g < 4; ++g) {
                *((f32x4*)&red[op][g][0][lane][0]) = acc[g][0];
                *((f32x4*)&red[op][g][1][lane][0]) = acc[g][1];
            }
        }
        __syncthreads();
        if (ks == 1) {
#pragma unroll
            for (int g = 0; g < 4; ++g) {
                f32x4 v0 = *((f32x4*)&red[op][g][0][lane][0]);
                f32x4 v1 = *((f32x4*)&red[op][g][1][lane][0]);
                v0 += acc[g][0];
                v1 += acc[g][1];
                *((f32x4*)&red[op][g][0][lane][0]) = v0;
                *((f32x4*)&red[op][g][1][lane][0]) = v1;
            }
        }
        __syncthreads();

        // ---- cell: 2 elements per thread ----
        {
            float C0[4], R0[4], C1[4], R1[4];
#pragma unroll
            for (int g = 0; g < 4; ++g) {
                C0[g] = red[0][g][0][ll][rr];
                R0[g] = red[1][g][0][ll][rr];
                C1[g] = red[0][g][1][ll][rr];
                R1[g] = red[1][g][1][ll][rr];
            }
            hbf *Hco, *Hro;
            if (layer == 0) {
                Hco = H0c_ring + (size_t)t * HSLOT;
                Hro = H0r_ring + (size_t)t * HSLOT;
            } else {
                Hco = (t & 1) ? H1c1 : H1c0;
                Hro = (t & 1) ? H1r1 : H1r0;
            }
            const bool writeF = (layer == 1) && (t == NF - 1);

            float nhl, nhu;
            cell_elem(C0, R0, bs, cAl, cAu, nhl, nhu);
            storeH(&Hco[idx0], 0.5f * (nhl + nhu));
            storeH(&Hro[idx0], 0.5f * (nhu - nhl));
            if (writeF) { h1l[idx0] = nhl; h1u[idx0] = nhu; }

            cell_elem(C1, R1, bs, cBl, cBu, nhl, nhu);
            storeH(&Hco[idx1], 0.5f * (nhl + nhu));
            storeH(&Hro[idx1], 0.5f * (nhu - nhl));
            if (writeF) { h1l[idx1] = nhl; h1u[idx1] = nhu; }
        }

        // ---- arrive: H stores complete, then bump own flag ----
        __builtin_amdgcn_s_waitcnt(0);
        __syncthreads();
        if (tid == 0)
            __hip_atomic_store(&flags[bid * 16], (unsigned)(t + 1),
                               __ATOMIC_RELAXED, __HIP_MEMORY_SCOPE_AGENT);
    }
}

// ---------------------------------------------------------------------------
// Final 512 -> 10 interval linear
// ---------------------------------------------------------------------------
__global__ __launch_bounds__(64) void final_kernel(
    const float* __restrict__ h1l, const float* __restrict__ h1u,
    const float* __restrict__ w, const float* __restrict__ bias,
    float* __restrict__ out)
{
    const int b = blockIdx.x;
    const int j = threadIdx.x;
    if (j < NOUT) {
        float oc = bias[j], orr = 0.f;
        for (int i = 0; i < HID2; ++i) {
            const float lo = h1l[(size_t)b * HID2 + i];
            const float hi = h1u[(size_t)b * HID2 + i];
            const float wv = w[i * NOUT + j];
            oc  = fmaf(0.5f * (lo + hi), wv, oc);
            orr = fmaf(0.5f * (hi - lo), fabsf(wv), orr);
        }
        out[b * NOUT + j] = oc - orr;
        out[BATCH * NOUT + b * NOUT + j] = oc + orr;
    }
}

// ---------------------------------------------------------------------------
extern "C" void kernel_launch(void* const* d_in, const int* in_sizes, int n_in,
                              void* d_out, int out_size, void* d_ws, size_t ws_size,
                              hipStream_t stream)
{
    const float* input_lb = (const float*)d_in[0];
    const float* input_ub = (const float*)d_in[1];
    const float* mtx1     = (const float*)d_in[2];
    const float* mtx2     = (const float*)d_in[3];
    const float* lin1_w   = (const float*)d_in[4];
    const float* lin1_b   = (const float*)d_in[5];
    const float* w_ih0    = (const float*)d_in[6];
    const float* w_hh0    = (const float*)d_in[7];
    const float* b0       = (const float*)d_in[8];
    const float* w_ih1    = (const float*)d_in[9];
    const float* w_hh1    = (const float*)d_in[10];
    const float* b1       = (const float*)d_in[11];
    const float* lin2_w   = (const float*)d_in[12];
    const float* lin2_b   = (const float*)d_in[13];
    float* out = (float*)d_out;

    char* ws = (char*)d_ws;
    size_t off = 0;
    hbf* Xc = (hbf*)(ws + off); off += (size_t)NF * HSLOT * 2;
    hbf* Xr = (hbf*)(ws + off); off += (size_t)NF * HSLOT * 2;
    hbf* Wt0 = (hbf*)(ws + off); off += (size_t)G4 * KTOT * 2;
    hbf* Wt1 = (hbf*)(ws + off); off += (size_t)G4 * KTOT * 2;

    hbf* H0c_ring = (hbf*)(ws + off); off += (size_t)(NF + 1) * HSLOT * 2;
    hbf* H0r_ring = (hbf*)(ws + off); off += (size_t)(NF + 1) * HSLOT * 2;

    // zeroed-every-launch region: H1 ping-pong + flags
    char* zbase = ws + off;
    hbf* H1c0 = (hbf*)(ws + off); off += (size_t)HSLOT * 2;
    hbf* H1r0 = (hbf*)(ws + off); off += (size_t)HSLOT * 2;
    hbf* H1c1 = (hbf*)(ws + off); off += (size_t)HSLOT * 2;
    hbf* H1r1 = (hbf*)(ws + off); off += (size_t)HSLOT * 2;
    unsigned* flags = (unsigned*)(ws + off); off += 256 * 64;
    const size_t zbytes = (size_t)((ws + off) - zbase);
    float* h1l = (float*)(ws + off); off += (size_t)HSLOT * 4;
    float* h1u = (float*)(ws + off); off += (size_t)HSLOT * 4;

    // zero: H1/flags region + the ring's zero slots (slot NF of each ring)
    hipMemsetAsync(zbase, 0, zbytes, stream);
    hipMemsetAsync(H0c_ring + (size_t)NF * HSLOT, 0, (size_t)HSLOT * 2, stream);
    hipMemsetAsync(H0r_ring + (size_t)NF * HSLOT, 0, (size_t)HSLOT * 2, stream);

    {
        const dim3 pgrid(G4 / 32, KTOT / 32);
        prep_weights_kernel<<<pgrid, 256, 0, stream>>>(w_ih0, w_hh0, Wt0);
        prep_weights_kernel<<<pgrid, 256, 0, stream>>>(w_ih1, w_hh1, Wt1);
    }

    frontend_kernel<<<(BATCH * NF) / 8, 512, 0, stream>>>(
        input_lb, input_ub, mtx1, mtx2, lin1_w, lin1_b, Xc, Xr);

    lstm_persistent<<<NBLK, 256, 0, stream>>>(
        Xc, Xr, Wt0, Wt1, b0, b1,
        H0c_ring, H0r_ring,
        H1c0, H1r0, H1c1, H1r1,
        h1l, h1u, flags);

    final_kernel<<<BATCH, 64, 0, stream>>>(h1l, h1u, lin2_w, lin2_b, out);
}